// Round 11
// baseline (297.207 us; speedup 1.0000x reference)
//
#include <hip/hip_runtime.h>
#include <stdint.h>

typedef unsigned short u16;
typedef __attribute__((ext_vector_type(8))) short short8;
typedef __attribute__((ext_vector_type(4))) float f32x4;

#define SEQ 2048
#define DM 1024
#define NB 4
#define ROWS (NB*SEQ)   // 8192

__device__ __forceinline__ u16 f2bf(float f) {
  union { float f; uint32_t u; } x; x.f = f;
  uint32_t u = x.u;
  uint32_t r = u + 0x7FFFu + ((u >> 16) & 1u);
  return (u16)(r >> 16);
}
__device__ __forceinline__ float bf2f(u16 h) {
  union { uint32_t u; float f; } x; x.u = ((uint32_t)h) << 16;
  return x.f;
}

__device__ __forceinline__ void g2l16(void* lds, const void* g) {
  __builtin_amdgcn_global_load_lds(
      (const __attribute__((address_space(1))) void*)g,
      (__attribute__((address_space(3))) void*)lds, 16, 0, 0);
}

// ---------------- fused convert: one kernel for all f32->bf16 staging ------
__global__ void k_cvt_all(const float* __restrict__ x,
                          const float* __restrict__ Wq, const float* __restrict__ Wk,
                          const float* __restrict__ Wv, const float* __restrict__ Wo,
                          const float* __restrict__ wb, u16* __restrict__ dws) {
  int i = blockIdx.x * 256 + threadIdx.x;   // f4 index, 4194304 total
  const float* src; long dst; bool ex = false;
  if (i < 2097152) { src = x + (long)i * 4; dst = (long)i * 4; }
  else if (i < 3145728) {
    int j = i - 2097152, which = j >> 18, o = j & 262143;
    const float* Wp = (which == 0) ? Wq : (which == 1) ? Wk : (which == 2) ? Wv : Wo;
    src = Wp + (long)o * 4; dst = 8388608 + (long)(j) * 4;
  } else { int j = i - 3145728; src = wb + (long)j * 4; dst = 12582912 + (long)j * 4; ex = true; }
  float4 v = *(const float4*)src;
  if (ex) { v.x = __expf(v.x); v.y = __expf(v.y); v.z = __expf(v.z); v.w = __expf(v.w); }
  ushort4 o4; o4.x = f2bf(v.x); o4.y = f2bf(v.y); o4.z = f2bf(v.z); o4.w = f2bf(v.w);
  *(ushort4*)(dws + dst) = o4;
}

// ---------------- 256xBN / BK=64 / 8-wave GEMM, m201-style 8-bar/tile -------
// R11: per-phase barrier pairs (4 phases/tile = 8 s_barrier/tile): each phase
// {ds-reads | SB | bar | lgkm0+SB | setprio MFMA cluster | SB | bar}.
// STAGE(t+2) issued in phase-4 pre-region (all tile-t ds_reads completed by
// ph3's closing barrier -> no buffer clobber; R6 invariant preserved).
// Counted vmcnt(8/6) at tile top; vmcnt(0) only at last tile. T2 swizzle.
// MODE 1: fused QKV epilogue (WM=4, BN=128, segments {Q:sigmoid,K,V}, bf16)
// MODE 2: f32 out + bias b0, ldc=1024 (out-proj, WM=4)
// MODE 3: AFT-ratio (WM=2): B-tile = 128 eKV rows + 128 eK rows, same e-cols;
//   epilogue out1 = sigQ * numer * rcp(denom) -> bf16.
#define SB __builtin_amdgcn_sched_barrier(0)
#define LGKM0 do { asm volatile("s_waitcnt lgkmcnt(0)" ::: "memory"); SB; } while (0)

#define STAGE(t_, bf_) do { \
  _Pragma("unroll") for (int c = 0; c < 4; ++c) { \
    int idx = c * 512 + tid; \
    int r = idx >> 3; \
    int ce = ((idx & 7) ^ (r & 7)) * 8; \
    g2l16(&lds[(bf_)*BUFE + idx*8], Ag + (long)r*KD + (t_)*64 + ce); \
  } \
  _Pragma("unroll") for (int c = 0; c < BN/64; ++c) { \
    int idx = c * 512 + tid; \
    int r = idx >> 3; \
    int ce = ((idx & 7) ^ (r & 7)) * 8; \
    const u16* bp_ = (MODE == 3 && c >= 2) ? (Bg + 896L*KD) : Bg; \
    g2l16(&lds[(bf_)*BUFE + 16384 + idx*8], bp_ + (long)r*KD + (t_)*64 + ce); \
  } } while (0)

#define LDA8(d_, mh_) do { \
  _Pragma("unroll") for (int i = 0; i < FM/2; ++i) \
  _Pragma("unroll") for (int k = 0; k < 2; ++k) \
    d_[i][k] = *(const short8*)&lds[ab + ((mh_)*(RW/2) + i*16 + lr)*64 + 8*(((k<<2)|kg) ^ (lr&7))]; \
  } while (0)

#define LDB8(nh_) do { \
  _Pragma("unroll") for (int j = 0; j < 2; ++j) \
  _Pragma("unroll") for (int k = 0; k < 2; ++k) { \
    int rowB_ = (MODE == 3) ? ((nh_)*128 + wn*32 + j*16 + lr) \
                            : (wn*64 + ((nh_)*2+j)*16 + lr); \
    bn[nh_][j][k] = *(const short8*)&lds[bb + rowB_*64 + 8*(((k<<2)|kg) ^ (lr&7))]; \
  } } while (0)

#define MMC(d_, mh_, nh_) do { \
  __builtin_amdgcn_s_setprio(1); \
  _Pragma("unroll") for (int i = 0; i < FM/2; ++i) \
  _Pragma("unroll") for (int j = 0; j < 2; ++j) \
  _Pragma("unroll") for (int k = 0; k < 2; ++k) \
    acc[(mh_)*(FM/2)+i][(nh_)*2+j] = __builtin_amdgcn_mfma_f32_16x16x32_bf16( \
        d_[i][k], bn[nh_][j][k], acc[(mh_)*(FM/2)+i][(nh_)*2+j], 0, 0, 0); \
  __builtin_amdgcn_s_setprio(0); \
  } while (0)

#define BAR __builtin_amdgcn_s_barrier()

template<int KD, int WM, int MODE>
__global__ __launch_bounds__(512)
void k_big(const u16* __restrict__ A, const u16* __restrict__ B,
           void* __restrict__ Cv,
           const float* __restrict__ b0, const float* __restrict__ b1,
           const float* __restrict__ b2, long sB, long sC)
{
  constexpr int WN = 8 / WM;           // waves in N
  constexpr int BN = WN * 64;          // 256 or 128
  constexpr int RW = 256 / WM;         // rows per wave: 128 or 64
  constexpr int FM = RW / 16;          // m-frags per wave: 8 or 4
  constexpr int NT = KD / 64;
  constexpr int BUFE = (256 + BN) * 64;  // u16 elems per buffer
  __shared__ u16 lds[2 * BUFE];        // 128 KiB (BN=256) or 96 KiB (BN=128)
  const int tid = threadIdx.x;
  const int l  = tid & 63, wid = tid >> 6;
  const int wm = wid / WN, wn = wid % WN;
  const int lr = l & 15,  kg = l >> 4;
  const int brow = blockIdx.y * 256;
  const int bcol = blockIdx.x * ((MODE == 3) ? 128 : BN);
  const u16* Ag = A + (long)brow * KD;
  const u16* Bg = B + (long)blockIdx.z * sB + (long)bcol * KD;

  f32x4 acc[FM][4];
#pragma unroll
  for (int m = 0; m < FM; ++m)
#pragma unroll
    for (int n = 0; n < 4; ++n) acc[m][n] = (f32x4){0.f, 0.f, 0.f, 0.f};

  short8 a0[FM/2][2], a1[FM/2][2], bn[2][2][2];

  STAGE(0, 0);
  STAGE(1, 1);

  for (int t = 0; t < NT; ++t) {
    const int bf = t & 1;
    if (t == NT - 1)              asm volatile("s_waitcnt vmcnt(0)" ::: "memory");
    else if constexpr (BN == 256) asm volatile("s_waitcnt vmcnt(8)" ::: "memory");
    else                          asm volatile("s_waitcnt vmcnt(6)" ::: "memory");
    BAR; SB;                              // tile top: buffer bf ready
    const int ab = bf*BUFE + wm*RW*64;
    const int bb = bf*BUFE + 16384;
    // ---- phase 1: quadrant (0,0) ----
    LDA8(a0, 0); LDB8(0); SB;
    BAR; LGKM0;
    MMC(a0, 0, 0); SB;
    BAR; SB;
    // ---- phase 2: quadrant (0,1) ----
    LDB8(1); SB;
    BAR; LGKM0;
    MMC(a0, 0, 1); SB;
    BAR; SB;
    // ---- phase 3: quadrant (1,1) ----
    LDA8(a1, 1); SB;
    BAR; LGKM0;
    MMC(a1, 1, 1); SB;
    BAR; SB;
    // ---- phase 4: quadrant (1,0); stage t+2 (all tile-t reads done) ----
    if (t + 2 < NT) STAGE(t + 2, bf);
    SB;
    BAR; SB;
    MMC(a1, 1, 0); SB;
    // closing barrier = next tile's top barrier
  }

  if constexpr (MODE == 3) {
    const u16* QsP = (const u16*)b0;
    u16* O = (u16*)Cv;
    const long rb = (long)blockIdx.z * 2048;
#pragma unroll
    for (int m = 0; m < FM; ++m)
#pragma unroll
      for (int j = 0; j < 2; ++j)
#pragma unroll
        for (int r = 0; r < 4; ++r) {
          int row = brow + wm*RW + m*16 + kg*4 + r;
          int e = bcol + wn*32 + j*16 + lr;
          float nu = acc[m][j][r];
          float de = acc[m][2+j][r];
          float q = bf2f(QsP[(rb + row) * 1024 + e]);
          O[(rb + row) * 1024 + e] = f2bf(q * nu * __builtin_amdgcn_rcpf(de));
        }
  } else {
#pragma unroll
    for (int m = 0; m < FM; ++m)
#pragma unroll
      for (int n = 0; n < 4; ++n)
#pragma unroll
        for (int r = 0; r < 4; ++r) {
          int row = brow + wm*RW + m*16 + kg*4 + r;
          int col = bcol + wn*64 + n*16 + lr;
          float v = acc[m][n][r];
          if (MODE == 1) {
            int seg = col >> 10, colr = col & 1023;
            const float* bp = (seg == 0) ? b0 : (seg == 1) ? b1 : b2;
            v += bp[colr];
            if (seg == 0) v = 1.f / (1.f + __expf(-v));
            ((u16*)Cv)[(long)seg * 8388608 + (long)row * 1024 + colr] = f2bf(v);
          } else {
            ((float*)Cv)[(long)row * 1024 + col] = v + b0[col];
          }
        }
  }
}

// ---------------- transpose + exp: Kb,Vb [b*T+s, e] bf16 -> Z[b][{eKV,eK}][e][s] bf16
__global__ void k_trans(const u16* __restrict__ Kb, const u16* __restrict__ Vb,
                        u16* __restrict__ Z) {
  __shared__ u16 lk[64][65];
  __shared__ u16 lv[64][65];
  int s0 = blockIdx.x * 64, e0 = blockIdx.y * 64, b = blockIdx.z;
  int tx = threadIdx.x & 63, ty = threadIdx.x >> 6;
  const long baseIn = (long)b * SEQ * DM;
  for (int j = ty; j < 64; j += 4) {
    lk[j][tx] = Kb[baseIn + (long)(s0 + j) * DM + e0 + tx];
    lv[j][tx] = Vb[baseIn + (long)(s0 + j) * DM + e0 + tx];
  }
  __syncthreads();
  const long ob = (long)b * 2 * DM * SEQ;
  for (int j = ty; j < 64; j += 4) {
    int e = e0 + j;
    float kf = bf2f(lk[tx][j]);
    float vf = bf2f(lv[tx][j]);
    float ek = __expf(kf);
    Z[ob + (long)e * SEQ + s0 + tx]        = f2bf(ek * vf);
    Z[ob + (long)(DM + e) * SEQ + s0 + tx] = f2bf(ek);
  }
}

extern "C" void kernel_launch(void* const* d_in, const int* in_sizes, int n_in,
                              void* d_out, int out_size, void* d_ws, size_t ws_size,
                              hipStream_t stream)
{
  const float* x     = (const float*)d_in[0];
  const float* Wq    = (const float*)d_in[2];
  const float* bq    = (const float*)d_in[3];
  const float* Wk    = (const float*)d_in[4];
  const float* bk    = (const float*)d_in[5];
  const float* Wv    = (const float*)d_in[6];
  const float* bv    = (const float*)d_in[7];
  const float* Wo    = (const float*)d_in[8];
  const float* bo    = (const float*)d_in[9];
  const float* wbias = (const float*)d_in[10];

  char* ws = (char*)d_ws;
  u16*  xb  = (u16*)(ws);                      // 16.8 MB (reused as out1)
  u16*  Wqb = (u16*)(ws + 16777216);           // Wq/Wk/Wv contiguous = Wall[3072][1024]
  u16*  Wob = (u16*)(ws + 16777216 + 3 * 2097152);
  u16*  EW  = (u16*)(ws + 25165824);           // 8.4 MB
  u16*  Qs  = (u16*)(ws + 33554432);           // Qs/Kb/Vb contiguous (seg stride 8388608)
  u16*  Kb  = (u16*)(ws + 50331648);
  u16*  Vb  = (u16*)(ws + 67108864);
  u16*  Z   = (u16*)(ws + 83886080);           // 33.6 MB -> total 117.4 MB
  u16*  out1 = xb;

  // all f32->bf16 conversions in one kernel
  k_cvt_all<<<16384, 256, 0, stream>>>(x, Wq, Wk, Wv, Wo, wbias, (u16*)ws);

  // fused QKV projection: A=xb [8192,1024], B=Wall [3072,1024] -> Qs|Kb|Vb
  dim3 gqkv(3072 / 128, ROWS / 256, 1);
  k_big<1024, 4, 1><<<gqkv, 512, 0, stream>>>(xb, Wqb, Qs, bq, bk, bv, 0, 0);

  // transpose + exp into Z
  dim3 gt(SEQ / 64, DM / 64, NB);
  k_trans<<<gt, 256, 0, stream>>>(Kb, Vb, Z);

  // AFT core + ratio + sigmoid-Q combine, fused: out1 = sigQ * numer/denom
  dim3 g8(8, 8, NB);
  k_big<2048, 2, 3><<<g8, 512, 0, stream>>>(EW, Z, out1, (const float*)Qs,
                                            nullptr, nullptr,
                                            (long)2 * DM * SEQ, 0);

  // output projection -> f32 d_out
  dim3 gop(DM / 128, ROWS / 256, 1);
  k_big<1024, 4, 2><<<gop, 512, 0, stream>>>(out1, Wob, (float*)d_out, bo, nullptr,
                                             nullptr, 0, 0);
}

// Round 12
// 274.167 us; speedup vs baseline: 1.0840x; 1.0840x over previous
//
#include <hip/hip_runtime.h>
#include <stdint.h>

typedef unsigned short u16;
typedef __attribute__((ext_vector_type(8))) short short8;
typedef __attribute__((ext_vector_type(4))) float f32x4;

#define SEQ 2048
#define DM 1024
#define NB 4
#define ROWS (NB*SEQ)   // 8192

__device__ __forceinline__ u16 f2bf(float f) {
  union { float f; uint32_t u; } x; x.f = f;
  uint32_t u = x.u;
  uint32_t r = u + 0x7FFFu + ((u >> 16) & 1u);
  return (u16)(r >> 16);
}
__device__ __forceinline__ float bf2f(u16 h) {
  union { uint32_t u; float f; } x; x.u = ((uint32_t)h) << 16;
  return x.f;
}

__device__ __forceinline__ void g2l16(void* lds, const void* g) {
  __builtin_amdgcn_global_load_lds(
      (const __attribute__((address_space(1))) void*)g,
      (__attribute__((address_space(3))) void*)lds, 16, 0, 0);
}

// ---------------- fused convert: all f32->bf16 staging ---------------------
// R12: Wk/Wv rows are INTERLEAVED into Wall: row 1024+2e = Wk row e,
// row 1025+2e = Wv row e (Q rows 0-1023, Wo rows 3072-4095 unchanged).
__global__ void k_cvt_all(const float* __restrict__ x,
                          const float* __restrict__ Wq, const float* __restrict__ Wk,
                          const float* __restrict__ Wv, const float* __restrict__ Wo,
                          const float* __restrict__ wb, u16* __restrict__ dws) {
  int i = blockIdx.x * 256 + threadIdx.x;   // f4 index, 4194304 total
  const float* src; long dst; bool ex = false;
  if (i < 2097152) { src = x + (long)i * 4; dst = (long)i * 4; }
  else if (i < 3145728) {
    int j = i - 2097152, w = j >> 18, o = j & 262143;
    const float* Wp = (w == 0) ? Wq : (w == 1) ? Wk : (w == 2) ? Wv : Wo;
    src = Wp + (long)o * 4;
    int e = o >> 8, c = o & 255;
    int rowIdx = (w == 0) ? e : (w == 3) ? (3072 + e) : (1024 + 2 * e + (w - 1));
    dst = 8388608 + (long)rowIdx * 1024 + c * 4;
  } else { int j = i - 3145728; src = wb + (long)j * 4; dst = 12582912 + (long)j * 4; ex = true; }
  float4 v = *(const float4*)src;
  if (ex) { v.x = __expf(v.x); v.y = __expf(v.y); v.z = __expf(v.z); v.w = __expf(v.w); }
  ushort4 o4; o4.x = f2bf(v.x); o4.y = f2bf(v.y); o4.z = f2bf(v.z); o4.w = f2bf(v.w);
  *(ushort4*)(dws + dst) = o4;
}

// ---------------- 256xBN / BK=64 / 8-wave GEMM (R9-verified schedule) -------
// C[m,n] = sum_k A[m,k] * B[n,k]; A:[M,KD] B:[N,KD] row-major bf16.
// T2 swizzle both-sides, counted vmcnt, setprio clusters, STAGE pinned below
// the bottom s_barrier (R6 race fix). Loop body = R9 exactly (best measured).
// MODE 1 (WM=4, BN=128): QKV. Block cols <1024: Q -> sigmoid -> Qs.
//   Cols >=1024 (interleaved K/V): even col 1024+2e = K_e, odd = V_e.
//   Epilogue: shfl_xor(1) pairs k,v in-lane; even lanes write eK=exp(k+bk)
//   and eKV=eK*(v+bv) TRANSPOSED into Z[b][{eKV:e, eK:DM+e}][s]. Replaces
//   the former k_trans kernel (saves 67 MB round-trip + 1 dispatch).
// MODE 2 (WM=4): f32 out + bias b0, ldc=1024 (out-proj).
// MODE 3 (WM=2): AFT-ratio; B-tile = 128 eKV rows + 128 eK rows, same e-cols;
//   epilogue out1 = sigQ * numer * rcp(denom) -> bf16.
#define SB __builtin_amdgcn_sched_barrier(0)

#define STAGE(t_, bf_) do { \
  _Pragma("unroll") for (int c = 0; c < 4; ++c) { \
    int idx = c * 512 + tid; \
    int r = idx >> 3; \
    int ce = ((idx & 7) ^ (r & 7)) * 8; \
    g2l16(&lds[(bf_)*BUFE + idx*8], Ag + (long)r*KD + (t_)*64 + ce); \
  } \
  _Pragma("unroll") for (int c = 0; c < BN/64; ++c) { \
    int idx = c * 512 + tid; \
    int r = idx >> 3; \
    int ce = ((idx & 7) ^ (r & 7)) * 8; \
    const u16* bp_ = (MODE == 3 && c >= 2) ? (Bg + 896L*KD) : Bg; \
    g2l16(&lds[(bf_)*BUFE + 16384 + idx*8], bp_ + (long)r*KD + (t_)*64 + ce); \
  } } while (0)

#define LDA8(d_, mh_) do { \
  _Pragma("unroll") for (int i = 0; i < FM/2; ++i) \
  _Pragma("unroll") for (int k = 0; k < 2; ++k) \
    d_[i][k] = *(const short8*)&lds[ab + ((mh_)*(RW/2) + i*16 + lr)*64 + 8*(((k<<2)|kg) ^ (lr&7))]; \
  } while (0)

#define LDB8(nh_) do { \
  _Pragma("unroll") for (int j = 0; j < 2; ++j) \
  _Pragma("unroll") for (int k = 0; k < 2; ++k) { \
    int rowB_ = (MODE == 3) ? ((nh_)*128 + wn*32 + j*16 + lr) \
                            : (wn*64 + ((nh_)*2+j)*16 + lr); \
    bn[nh_][j][k] = *(const short8*)&lds[bb + rowB_*64 + 8*(((k<<2)|kg) ^ (lr&7))]; \
  } } while (0)

#define MM8(d_, mh_, nh_) do { \
  asm volatile("s_waitcnt lgkmcnt(0)" ::: "memory"); \
  SB; \
  __builtin_amdgcn_s_setprio(1); \
  _Pragma("unroll") for (int i = 0; i < FM/2; ++i) \
  _Pragma("unroll") for (int j = 0; j < 2; ++j) \
  _Pragma("unroll") for (int k = 0; k < 2; ++k) \
    acc[(mh_)*(FM/2)+i][(nh_)*2+j] = __builtin_amdgcn_mfma_f32_16x16x32_bf16( \
        d_[i][k], bn[nh_][j][k], acc[(mh_)*(FM/2)+i][(nh_)*2+j], 0, 0, 0); \
  __builtin_amdgcn_s_setprio(0); \
  } while (0)

template<int KD, int WM, int MODE>
__global__ __launch_bounds__(512)
void k_big(const u16* __restrict__ A, const u16* __restrict__ B,
           void* __restrict__ Cv,
           const float* __restrict__ b0, const float* __restrict__ b1,
           const float* __restrict__ b2, void* __restrict__ aux,
           long sB, long sC)
{
  constexpr int WN = 8 / WM;           // waves in N
  constexpr int BN = WN * 64;          // 256 or 128
  constexpr int RW = 256 / WM;         // rows per wave: 128 or 64
  constexpr int FM = RW / 16;          // m-frags per wave: 8 or 4
  constexpr int NT = KD / 64;
  constexpr int BUFE = (256 + BN) * 64;  // u16 elems per buffer
  __shared__ u16 lds[2 * BUFE];        // 128 KiB (BN=256) or 96 KiB (BN=128)
  const int tid = threadIdx.x;
  const int l  = tid & 63, wid = tid >> 6;
  const int wm = wid / WN, wn = wid % WN;
  const int lr = l & 15,  kg = l >> 4;
  const int brow = blockIdx.y * 256;
  const int bcol = blockIdx.x * ((MODE == 3) ? 128 : BN);
  const u16* Ag = A + (long)brow * KD;
  const u16* Bg = B + (long)blockIdx.z * sB + (long)bcol * KD;

  f32x4 acc[FM][4];
#pragma unroll
  for (int m = 0; m < FM; ++m)
#pragma unroll
    for (int n = 0; n < 4; ++n) acc[m][n] = (f32x4){0.f, 0.f, 0.f, 0.f};

  short8 a0[FM/2][2], a1[FM/2][2], bn[2][2][2];

  STAGE(0, 0);
  STAGE(1, 1);

  for (int t = 0; t < NT; ++t) {
    const int bf = t & 1;
    if (t == NT - 1)              asm volatile("s_waitcnt vmcnt(0)" ::: "memory");
    else if constexpr (BN == 256) asm volatile("s_waitcnt vmcnt(8)" ::: "memory");
    else                          asm volatile("s_waitcnt vmcnt(6)" ::: "memory");
    __builtin_amdgcn_s_barrier();
    SB;
    const int ab = bf*BUFE + wm*RW*64;
    const int bb = bf*BUFE + 16384;
    LDA8(a0, 0); LDB8(0); MM8(a0, 0, 0);
    LDB8(1);              MM8(a0, 0, 1);
    LDA8(a1, 1);          MM8(a1, 1, 1);
                          MM8(a1, 1, 0);
    SB;
    __builtin_amdgcn_s_barrier();
    SB;                                  // R6 race fix: pin STAGE below barrier
    if (t + 2 < NT) STAGE(t + 2, bf);
  }

  if constexpr (MODE == 3) {
    const u16* QsP = (const u16*)b0;
    u16* O = (u16*)Cv;
    const long rb = (long)blockIdx.z * 2048;
#pragma unroll
    for (int m = 0; m < FM; ++m)
#pragma unroll
      for (int j = 0; j < 2; ++j)
#pragma unroll
        for (int r = 0; r < 4; ++r) {
          int row = brow + wm*RW + m*16 + kg*4 + r;
          int e = bcol + wn*32 + j*16 + lr;
          float nu = acc[m][j][r];
          float de = acc[m][2+j][r];
          float q = bf2f(QsP[(rb + row) * 1024 + e]);
          O[(rb + row) * 1024 + e] = f2bf(q * nu * __builtin_amdgcn_rcpf(de));
        }
  } else if constexpr (MODE == 1) {
    if (bcol < 1024) {
      // Q segment -> sigmoid -> Qs
#pragma unroll
      for (int m = 0; m < FM; ++m)
#pragma unroll
        for (int n = 0; n < 4; ++n)
#pragma unroll
          for (int r = 0; r < 4; ++r) {
            int row = brow + wm*RW + m*16 + kg*4 + r;
            int col = bcol + wn*64 + n*16 + lr;
            float v = acc[m][n][r] + b0[col];
            v = 1.f / (1.f + __expf(-v));
            ((u16*)Cv)[(long)row * 1024 + col] = f2bf(v);
          }
    } else {
      // interleaved K/V segment -> eK, eKV transposed into Z
      u16* Zp = (u16*)aux;
      int colr = bcol + wn*64 - 1024;    // block-local base within K/V region
#pragma unroll
      for (int m = 0; m < FM; ++m) {
        int row0 = brow + wm*RW + m*16 + kg*4;
        int b = row0 >> 11, s0 = row0 & 2047;
        u16* Zb = Zp + (long)b * 2 * DM * SEQ;
#pragma unroll
        for (int n = 0; n < 4; ++n) {
          int cl = colr + n*16 + lr;
          int e = cl >> 1;
          bool isK = (cl & 1) == 0;
          float bias = isK ? b1[e] : b2[e];
          ushort4 ekO, ekvO;
#pragma unroll
          for (int r = 0; r < 4; ++r) {
            float vb = acc[m][n][r] + bias;
            float partner = __shfl_xor(vb, 1);
            float ek = __expf(vb);            // valid on even (K) lanes
            float ekv = ek * partner;
            ((u16*)&ekO)[r]  = f2bf(ek);
            ((u16*)&ekvO)[r] = f2bf(ekv);
          }
          if (isK) {
            *(ushort4*)&Zb[(long)(DM + e) * SEQ + s0] = ekO;
            *(ushort4*)&Zb[(long)e * SEQ + s0]        = ekvO;
          }
        }
      }
    }
  } else {
#pragma unroll
    for (int m = 0; m < FM; ++m)
#pragma unroll
      for (int n = 0; n < 4; ++n)
#pragma unroll
        for (int r = 0; r < 4; ++r) {
          int row = brow + wm*RW + m*16 + kg*4 + r;
          int col = bcol + wn*64 + n*16 + lr;
          ((float*)Cv)[(long)row * 1024 + col] = acc[m][n][r] + b0[col];
        }
  }
}

extern "C" void kernel_launch(void* const* d_in, const int* in_sizes, int n_in,
                              void* d_out, int out_size, void* d_ws, size_t ws_size,
                              hipStream_t stream)
{
  const float* x     = (const float*)d_in[0];
  const float* Wq    = (const float*)d_in[2];
  const float* bq    = (const float*)d_in[3];
  const float* Wk    = (const float*)d_in[4];
  const float* bk    = (const float*)d_in[5];
  const float* Wv    = (const float*)d_in[6];
  const float* bv    = (const float*)d_in[7];
  const float* Wo    = (const float*)d_in[8];
  const float* bo    = (const float*)d_in[9];
  const float* wbias = (const float*)d_in[10];

  char* ws = (char*)d_ws;
  u16*  xb  = (u16*)(ws);                      // 16.8 MB (reused as out1)
  u16*  Wqb = (u16*)(ws + 16777216);           // Wall[4096][1024]: Q | K/V interleaved | Wo
  u16*  Wob = (u16*)(ws + 16777216 + 3 * 2097152);
  u16*  EW  = (u16*)(ws + 25165824);           // 8.4 MB
  u16*  Qs  = (u16*)(ws + 33554432);           // 16.8 MB
  u16*  Z   = (u16*)(ws + 83886080);           // 33.6 MB (written by QKV epilogue)
  u16*  out1 = xb;

  // all f32->bf16 conversions (K/V weight rows interleaved into Wall)
  k_cvt_all<<<16384, 256, 0, stream>>>(x, Wq, Wk, Wv, Wo, wbias, (u16*)ws);

  // fused QKV projection + exp/transpose epilogue: writes Qs and Z directly
  dim3 gqkv(3072 / 128, ROWS / 256, 1);
  k_big<1024, 4, 1><<<gqkv, 512, 0, stream>>>(xb, Wqb, Qs, bq, bk, bv, Z, 0, 0);

  // AFT core + ratio + sigmoid-Q combine, fused: out1 = sigQ * numer/denom
  dim3 g8(8, 8, NB);
  k_big<2048, 2, 3><<<g8, 512, 0, stream>>>(EW, Z, out1, (const float*)Qs,
                                            nullptr, nullptr, nullptr,
                                            (long)2 * DM * SEQ, 0);

  // output projection -> f32 d_out
  dim3 gop(DM / 128, ROWS / 256, 1);
  k_big<1024, 4, 2><<<gop, 512, 0, stream>>>(out1, Wob, (float*)d_out, bo, nullptr,
                                             nullptr, nullptr, 0, 0);
}